// Round 4
// baseline (453.332 us; speedup 1.0000x reference)
//
#include <hip/hip_runtime.h>

#define BATCH 64
#define TLEN 1000
#define F 128
#define S 10
#define L 100           // TLEN / S
#define NPAIR 8128      // F*(F-1)/2
#define NTILE 528       // 32*33/2 lower-tri 4x4 tile grid incl. diagonal
#define NT4 (NPAIR / 4) // 2032 float4s per window
#define BLOCK 512

// corr[i][j] = (sum_s x_i x_j / S - m_i m_j) * q_i q_j,  q = (std==0) ? 0 : 1/std
// Window (5 KB) is read from GLOBAL in the tile loop (L1-hot after the stats
// pass) so the TA pipe carries operand reads while the LDS pipe carries only
// the packed-triangle staging and the HBM pipe drains the coalesced flush.
__global__ __launch_bounds__(BLOCK, 8) void corr_kernel(const float* __restrict__ x,
                                                        float* __restrict__ out) {
    const int win = blockIdx.x;          // 0 .. BATCH*L-1
    const int b = win / L;
    const int l = win % L;
    const int tid = threadIdx.x;

    const float* __restrict__ w = x + ((size_t)b * TLEN + (size_t)l * S) * F;

    __shared__ float mean_s[F];
    __shared__ float q_s[F];
    __shared__ __align__(16) float tri[NPAIR];   // packed lower triangle (32.5 KB)

    // ---- phase 1: per-feature mean & 1/std (threads 0..127), warms window into L1/L2 ----
    if (tid < F) {
        const int f = tid;
        float v[S];
        float sum = 0.f;
        #pragma unroll
        for (int s = 0; s < S; ++s) { v[s] = w[s * F + f]; sum += v[s]; }  // 256B coalesced per s
        const float mean = sum * (1.0f / S);
        float sq = 0.f;
        #pragma unroll
        for (int s = 0; s < S; ++s) { const float d = v[s] - mean; sq += d * d; }
        const float stdv = sqrtf(sq * (1.0f / S));
        mean_s[f] = mean;
        q_s[f] = (stdv == 0.f) ? 0.f : 1.0f / stdv;
    }
    __syncthreads();

    // ---- phase 2: lower-triangle 4x4 register tiles (global float4 reads, L1-hit) ----
    for (int t = tid; t < NTILE; t += BLOCK) {
        int ti = (int)((sqrtf(8.0f * (float)t + 1.0f) - 1.0f) * 0.5f);
        while ((ti + 1) * (ti + 2) / 2 <= t) ++ti;
        while (ti * (ti + 1) / 2 > t) --ti;
        const int tj = t - ti * (ti + 1) / 2;

        float acc[4][4];
        #pragma unroll
        for (int a = 0; a < 4; ++a)
            #pragma unroll
            for (int c = 0; c < 4; ++c) acc[a][c] = 0.f;

        #pragma unroll
        for (int s = 0; s < S; ++s) {
            const float4 av = *(const float4*)(w + s * F + ti * 4);
            const float4 bv = *(const float4*)(w + s * F + tj * 4);
            const float a0[4] = {av.x, av.y, av.z, av.w};
            const float b0[4] = {bv.x, bv.y, bv.z, bv.w};
            #pragma unroll
            for (int di = 0; di < 4; ++di)
                #pragma unroll
                for (int dj = 0; dj < 4; ++dj)
                    acc[di][dj] += a0[di] * b0[dj];
        }

        float mi[4], mj[4], qi[4], qj[4];
        #pragma unroll
        for (int d = 0; d < 4; ++d) {
            mi[d] = mean_s[ti * 4 + d]; qi[d] = q_s[ti * 4 + d];
            mj[d] = mean_s[tj * 4 + d]; qj[d] = q_s[tj * 4 + d];
        }

        // scalar LDS writes; rotate dj by lane to break the stride-4 bank pattern
        #pragma unroll
        for (int di = 0; di < 4; ++di) {
            const int i = ti * 4 + di;
            const int rowoff = i * (i - 1) / 2 + tj * 4;
            #pragma unroll
            for (int k = 0; k < 4; ++k) {
                const int dj = (k + tid) & 3;
                const int j = tj * 4 + dj;
                if (j < i) {
                    tri[rowoff + dj] = (acc[di][dj] * (1.0f / S) - mi[di] * mj[dj]) * (qi[di] * qj[dj]);
                }
            }
        }
    }
    __syncthreads();

    // ---- phase 3: contiguous float4 LDS->global flush, fully coalesced ----
    const float4* t4 = (const float4*)tri;
    float4* o4 = (float4*)(out + (size_t)win * NPAIR);
    for (int p = tid; p < NT4; p += BLOCK) o4[p] = t4[p];
}

extern "C" void kernel_launch(void* const* d_in, const int* in_sizes, int n_in,
                              void* d_out, int out_size, void* d_ws, size_t ws_size,
                              hipStream_t stream) {
    const float* x = (const float*)d_in[0];
    float* out = (float*)d_out;
    corr_kernel<<<BATCH * L, BLOCK, 0, stream>>>(x, out);
}